// Round 2
// baseline (1719.500 us; speedup 1.0000x reference)
//
#include <hip/hip_runtime.h>

#define IN_F 256
#define OUT_F 64

// ---------------- fc: h = x @ W + b ----------------
// block = 256 threads (4 waves). W (256x64 f32 = 64KB) staged in LDS.
// lane = output feature f (0..63) -> W reads coalesced & bank-conflict-free
// (64 consecutive dwords/wave = 2 lanes/bank = free).
// Each wave register-blocks 8 rows: one ds_read of W[k][f] feeds 8 FMAs.
// x read as broadcast float4 (all lanes in a wave read the same 16B).
__global__ __launch_bounds__(256, 2)
void fc_kernel(const float* __restrict__ x, const float* __restrict__ W,
               const float* __restrict__ b, float* __restrict__ h, int nRows) {
    __shared__ float Wl[IN_F * OUT_F];  // 64 KiB
    {
        const float4* W4 = (const float4*)W;
        float4* Wl4 = (float4*)Wl;
        #pragma unroll
        for (int i = 0; i < (IN_F * OUT_F / 4) / 256; ++i)  // 16 iters
            Wl4[threadIdx.x + i * 256] = W4[threadIdx.x + i * 256];
    }
    __syncthreads();

    const int f = threadIdx.x & 63;
    const int wv = threadIdx.x >> 6;
    const float bias = b[f];
    const int ROWS = 8;

    for (int r0 = (blockIdx.x * 4 + wv) * ROWS; r0 < nRows;
         r0 += gridDim.x * 4 * ROWS) {
        float acc[ROWS];
        #pragma unroll
        for (int r = 0; r < ROWS; ++r) acc[r] = bias;

        if (r0 + ROWS <= nRows) {
            const float* xr = x + (size_t)r0 * IN_F;
            for (int k = 0; k < IN_F; k += 4) {
                float w0 = Wl[(k + 0) * OUT_F + f];
                float w1 = Wl[(k + 1) * OUT_F + f];
                float w2 = Wl[(k + 2) * OUT_F + f];
                float w3 = Wl[(k + 3) * OUT_F + f];
                #pragma unroll
                for (int r = 0; r < ROWS; ++r) {
                    float4 xv = *(const float4*)(xr + r * IN_F + k);
                    acc[r] = fmaf(xv.x, w0, acc[r]);
                    acc[r] = fmaf(xv.y, w1, acc[r]);
                    acc[r] = fmaf(xv.z, w2, acc[r]);
                    acc[r] = fmaf(xv.w, w3, acc[r]);
                }
            }
            #pragma unroll
            for (int r = 0; r < ROWS; ++r)
                h[(size_t)(r0 + r) * OUT_F + f] = acc[r];
        } else {
            for (int r = 0; r + r0 < nRows; ++r) {
                float a = bias;
                for (int k = 0; k < IN_F; ++k)
                    a = fmaf(x[(size_t)(r0 + r) * IN_F + k], Wl[k * OUT_F + f], a);
                h[(size_t)(r0 + r) * OUT_F + f] = a;
            }
        }
    }
}

// ---------------- scatter: out[dst] += w * h[src] ----------------
// 16 threads per edge, float4 per thread (16*4 = 64 feats).
// h gather: each edge reads a contiguous 256B segment (well coalesced).
// Output via native f32 atomics (fire-and-forget).
__global__ __launch_bounds__(256)
void scatter_kernel(const float* __restrict__ h, const int* __restrict__ src,
                    const int* __restrict__ dst, const float* __restrict__ w,
                    float* __restrict__ out, int nE) {
    int t = blockIdx.x * 256 + threadIdx.x;
    int c = t & 15;
    int stride = (gridDim.x * 256) >> 4;
    for (int e = t >> 4; e < nE; e += stride) {
        int s = src[e];
        int d = dst[e];
        float ww = w[e];
        float4 hv = *(const float4*)(h + (size_t)s * OUT_F + c * 4);
        float* op = out + (size_t)d * OUT_F + c * 4;
        unsafeAtomicAdd(op + 0, ww * hv.x);
        unsafeAtomicAdd(op + 1, ww * hv.y);
        unsafeAtomicAdd(op + 2, ww * hv.z);
        unsafeAtomicAdd(op + 3, ww * hv.w);
    }
}

extern "C" void kernel_launch(void* const* d_in, const int* in_sizes, int n_in,
                              void* d_out, int out_size, void* d_ws, size_t ws_size,
                              hipStream_t stream) {
    const float* x    = (const float*)d_in[0];
    const int*   esrc = (const int*)d_in[1];
    const int*   edst = (const int*)d_in[2];
    const float* ew   = (const float*)d_in[3];
    const float* W    = (const float*)d_in[4];
    const float* b    = (const float*)d_in[5];

    int nRows = in_sizes[0] / IN_F;   // 100000
    int nE    = in_sizes[1];          // 1600000

    float* h   = (float*)d_ws;        // 100000*64*4 = 25.6 MB scratch
    float* out = (float*)d_out;

    hipMemsetAsync(out, 0, (size_t)out_size * sizeof(float), stream);

    int fcBlocks = (nRows + 31) / 32;  // 32 rows per block (4 waves * 8 rows)
    fc_kernel<<<fcBlocks, 256, 0, stream>>>(x, W, b, h, nRows);

    scatter_kernel<<<4096, 256, 0, stream>>>(h, esrc, edst, ew, out, nE);
}

// Round 3
// 641.212 us; speedup vs baseline: 2.6816x; 2.6816x over previous
//
#include <hip/hip_runtime.h>

#define IN_F 256
#define OUT_F 64

// ---------------- fc: h = x @ W + b ----------------
// 1024 threads (16 waves) share one 64KB W stage in LDS -> 16 waves/CU
// (vs 8 before). lane = output feature; 8 rows/wave register-blocked;
// x loads double-buffered in registers to break the load->FMA latency chain.
__global__ __launch_bounds__(1024, 4)
void fc_kernel(const float* __restrict__ x, const float* __restrict__ W,
               const float* __restrict__ b, float* __restrict__ h, int nRows) {
    __shared__ float Wl[IN_F * OUT_F];  // 64 KiB
    {
        const float4* W4 = (const float4*)W;
        float4* Wl4 = (float4*)Wl;
        #pragma unroll
        for (int i = 0; i < (IN_F * OUT_F / 4) / 1024; ++i)  // 4 iters
            Wl4[threadIdx.x + i * 1024] = W4[threadIdx.x + i * 1024];
    }
    __syncthreads();

    const int f = threadIdx.x & 63;
    const int wv = threadIdx.x >> 6;
    const float bias = b[f];
    const int ROWS = 8;

    int r0 = (blockIdx.x * 16 + wv) * ROWS;
    if (r0 >= nRows) return;

    if (r0 + ROWS <= nRows) {
        const float* xr = x + (size_t)r0 * IN_F;
        float acc[ROWS];
        #pragma unroll
        for (int r = 0; r < ROWS; ++r) acc[r] = bias;

        float4 xa[ROWS], xb[ROWS];
        #pragma unroll
        for (int r = 0; r < ROWS; ++r) xa[r] = *(const float4*)(xr + r * IN_F);

        // k loop unrolled by 8: compute on one buffer while loading the other
        for (int k = 0; k < IN_F; k += 8) {
            #pragma unroll
            for (int r = 0; r < ROWS; ++r)
                xb[r] = *(const float4*)(xr + r * IN_F + k + 4);
            {
                float w0 = Wl[(k + 0) * OUT_F + f];
                float w1 = Wl[(k + 1) * OUT_F + f];
                float w2 = Wl[(k + 2) * OUT_F + f];
                float w3 = Wl[(k + 3) * OUT_F + f];
                #pragma unroll
                for (int r = 0; r < ROWS; ++r) {
                    acc[r] = fmaf(xa[r].x, w0, acc[r]);
                    acc[r] = fmaf(xa[r].y, w1, acc[r]);
                    acc[r] = fmaf(xa[r].z, w2, acc[r]);
                    acc[r] = fmaf(xa[r].w, w3, acc[r]);
                }
            }
            if (k + 8 < IN_F) {
                #pragma unroll
                for (int r = 0; r < ROWS; ++r)
                    xa[r] = *(const float4*)(xr + r * IN_F + k + 8);
            }
            {
                float w0 = Wl[(k + 4) * OUT_F + f];
                float w1 = Wl[(k + 5) * OUT_F + f];
                float w2 = Wl[(k + 6) * OUT_F + f];
                float w3 = Wl[(k + 7) * OUT_F + f];
                #pragma unroll
                for (int r = 0; r < ROWS; ++r) {
                    acc[r] = fmaf(xb[r].x, w0, acc[r]);
                    acc[r] = fmaf(xb[r].y, w1, acc[r]);
                    acc[r] = fmaf(xb[r].z, w2, acc[r]);
                    acc[r] = fmaf(xb[r].w, w3, acc[r]);
                }
            }
        }
        #pragma unroll
        for (int r = 0; r < ROWS; ++r)
            h[(size_t)(r0 + r) * OUT_F + f] = acc[r];
    } else {
        for (int r = 0; r + r0 < nRows; ++r) {
            float a = bias;
            for (int k = 0; k < IN_F; ++k)
                a = fmaf(x[(size_t)(r0 + r) * IN_F + k], Wl[k * OUT_F + f], a);
            h[(size_t)(r0 + r) * OUT_F + f] = a;
        }
    }
}

// ---------------- CSR build ----------------
__global__ __launch_bounds__(256)
void hist_kernel(const int* __restrict__ dst, int* __restrict__ cnt, int nE) {
    for (int i = blockIdx.x * blockDim.x + threadIdx.x; i < nE;
         i += gridDim.x * blockDim.x)
        atomicAdd(&cnt[dst[i]], 1);
}

// pass 1: per-block (1024 elems) exclusive scan + block totals
__global__ __launch_bounds__(256)
void scan1_kernel(const int* __restrict__ cnt, int* __restrict__ off,
                  int* __restrict__ part, int n) {
    __shared__ int sh[256];
    int base = blockIdx.x * 1024;
    int t = threadIdx.x;
    int v[4]; int s = 0;
    #pragma unroll
    for (int i = 0; i < 4; ++i) {
        int idx = base + t * 4 + i;
        v[i] = (idx < n) ? cnt[idx] : 0;
        s += v[i];
    }
    sh[t] = s;
    __syncthreads();
    for (int d = 1; d < 256; d <<= 1) {
        int val = (t >= d) ? sh[t - d] : 0;
        __syncthreads();
        sh[t] += val;
        __syncthreads();
    }
    if (t == 255) part[blockIdx.x] = sh[255];
    int run = (t == 0) ? 0 : sh[t - 1];
    #pragma unroll
    for (int i = 0; i < 4; ++i) {
        int idx = base + t * 4 + i;
        if (idx < n) off[idx] = run;
        run += v[i];
    }
}

// pass 2: exclusive scan of <=128 block totals, one block
__global__ __launch_bounds__(128)
void scan2_kernel(int* __restrict__ part, int nPart) {
    __shared__ int sh[128];
    int t = threadIdx.x;
    sh[t] = (t < nPart) ? part[t] : 0;
    __syncthreads();
    for (int d = 1; d < 128; d <<= 1) {
        int val = (t >= d) ? sh[t - d] : 0;
        __syncthreads();
        sh[t] += val;
        __syncthreads();
    }
    if (t < nPart) part[t] = (t == 0) ? 0 : sh[t - 1];
}

// pass 3: add block bases
__global__ __launch_bounds__(256)
void scan3_kernel(int* __restrict__ off, const int* __restrict__ part, int n) {
    for (int i = blockIdx.x * blockDim.x + threadIdx.x; i < n;
         i += gridDim.x * blockDim.x)
        off[i] += part[i >> 10];
}

// slot-fill: pack (src, weight) per edge into CSR order
__global__ __launch_bounds__(256)
void fill_kernel(const int* __restrict__ src, const int* __restrict__ dst,
                 const float* __restrict__ w, const int* __restrict__ off,
                 int* __restrict__ cur, int2* __restrict__ pack, int nE) {
    for (int i = blockIdx.x * blockDim.x + threadIdx.x; i < nE;
         i += gridDim.x * blockDim.x) {
        int d = dst[i];
        int p = off[d] + atomicAdd(&cur[d], 1);
        pack[p] = make_int2(src[i], __float_as_int(w[i]));
    }
}

// ---------------- gather: out[n] = sum_e w_e * h[src_e] ----------------
// one wave per node, lane = feature. 4-edge prefetch to break latency chain.
// Zero atomics; each output element written exactly once.
__global__ __launch_bounds__(256)
void gather_kernel(const float* __restrict__ h, const int* __restrict__ off,
                   const int2* __restrict__ pack, float* __restrict__ out,
                   int nNodes) {
    int wid = (blockIdx.x * 256 + threadIdx.x) >> 6;
    int lane = threadIdx.x & 63;
    if (wid >= nNodes) return;
    int e = off[wid], end = off[wid + 1];
    float acc = 0.f;
    for (; e + 4 <= end; e += 4) {
        int2 p0 = pack[e + 0];
        int2 p1 = pack[e + 1];
        int2 p2 = pack[e + 2];
        int2 p3 = pack[e + 3];
        float h0 = h[(size_t)p0.x * OUT_F + lane];
        float h1 = h[(size_t)p1.x * OUT_F + lane];
        float h2 = h[(size_t)p2.x * OUT_F + lane];
        float h3 = h[(size_t)p3.x * OUT_F + lane];
        acc = fmaf(__int_as_float(p0.y), h0, acc);
        acc = fmaf(__int_as_float(p1.y), h1, acc);
        acc = fmaf(__int_as_float(p2.y), h2, acc);
        acc = fmaf(__int_as_float(p3.y), h3, acc);
    }
    for (; e < end; ++e) {
        int2 p = pack[e];
        acc = fmaf(__int_as_float(p.y), h[(size_t)p.x * OUT_F + lane], acc);
    }
    out[(size_t)wid * OUT_F + lane] = acc;
}

// ---------------- fallback (atomic) scatter, used only if ws too small ----
__global__ __launch_bounds__(256)
void scatter_kernel(const float* __restrict__ h, const int* __restrict__ src,
                    const int* __restrict__ dst, const float* __restrict__ w,
                    float* __restrict__ out, int nE) {
    int t = blockIdx.x * 256 + threadIdx.x;
    int c = t & 15;
    int stride = (gridDim.x * 256) >> 4;
    for (int e = t >> 4; e < nE; e += stride) {
        int s = src[e];
        int d = dst[e];
        float ww = w[e];
        float4 hv = *(const float4*)(h + (size_t)s * OUT_F + c * 4);
        float* op = out + (size_t)d * OUT_F + c * 4;
        unsafeAtomicAdd(op + 0, ww * hv.x);
        unsafeAtomicAdd(op + 1, ww * hv.y);
        unsafeAtomicAdd(op + 2, ww * hv.z);
        unsafeAtomicAdd(op + 3, ww * hv.w);
    }
}

static inline size_t align256(size_t x) { return (x + 255) & ~(size_t)255; }

extern "C" void kernel_launch(void* const* d_in, const int* in_sizes, int n_in,
                              void* d_out, int out_size, void* d_ws, size_t ws_size,
                              hipStream_t stream) {
    const float* x    = (const float*)d_in[0];
    const int*   esrc = (const int*)d_in[1];
    const int*   edst = (const int*)d_in[2];
    const float* ew   = (const float*)d_in[3];
    const float* W    = (const float*)d_in[4];
    const float* b    = (const float*)d_in[5];

    int nRows = in_sizes[0] / IN_F;   // 100000
    int nE    = in_sizes[1];          // 1600000
    int nOff  = nRows + 1;

    // workspace layout
    char* p = (char*)d_ws;
    size_t hB    = align256((size_t)nRows * OUT_F * sizeof(float));
    size_t cntB  = align256((size_t)2 * nOff * sizeof(int));  // cnt + cur contiguous
    size_t offB  = align256((size_t)nOff * sizeof(int));
    size_t partB = align256(128 * sizeof(int));
    size_t packB = align256((size_t)nE * sizeof(int2));
    size_t need  = hB + cntB + offB + partB + packB;

    float* h = (float*)p;                 p += hB;
    int*  cnt = (int*)p;                  // [nOff] counts
    int*  cur = (int*)(p + (size_t)nOff * sizeof(int));  // [nOff] cursors
    p += cntB;
    int*  off = (int*)p;                  p += offB;
    int*  part = (int*)p;                 p += partB;
    int2* pack = (int2*)p;

    float* out = (float*)d_out;

    int fcBlocks = (nRows + 127) / 128;  // 1024 thr: 16 waves * 8 rows
    fc_kernel<<<fcBlocks, 1024, 0, stream>>>(x, W, b, h, nRows);

    if (ws_size >= need) {
        // CSR path (no f32 atomics)
        hipMemsetAsync(cnt, 0, (size_t)2 * nOff * sizeof(int), stream);
        hist_kernel<<<2048, 256, 0, stream>>>(edst, cnt, nE);
        int nPart = (nOff + 1023) / 1024;          // 98
        scan1_kernel<<<nPart, 256, 0, stream>>>(cnt, off, part, nOff);
        scan2_kernel<<<1, 128, 0, stream>>>(part, nPart);
        scan3_kernel<<<512, 256, 0, stream>>>(off, part, nOff);
        fill_kernel<<<2048, 256, 0, stream>>>(esrc, edst, ew, off, cur, pack, nE);
        int gBlocks = (nRows * 64 + 255) / 256;    // one wave per node
        gather_kernel<<<gBlocks, 256, 0, stream>>>(h, off, pack, out, nRows);
    } else {
        // fallback: atomic scatter
        hipMemsetAsync(out, 0, (size_t)out_size * sizeof(float), stream);
        scatter_kernel<<<4096, 256, 0, stream>>>(h, esrc, edst, ew, out, nE);
    }
}

// Round 4
// 415.092 us; speedup vs baseline: 4.1425x; 1.5447x over previous
//
#include <hip/hip_runtime.h>

#define IN_F 256
#define OUT_F 64

typedef __attribute__((ext_vector_type(8))) short short8;
typedef __attribute__((ext_vector_type(4))) float f32x4;

static __device__ __forceinline__ short f2bf(float f) {
    union { float f; unsigned u; } v; v.f = f;
    unsigned r = v.u + 0x7FFFu + ((v.u >> 16) & 1u);  // RNE
    return (short)(r >> 16);
}
static __device__ __forceinline__ float bf2f(short s) {
    return __int_as_float(((unsigned)(unsigned short)s) << 16);
}

// ---------------- prep: Wt[n][k] = bf16(W[k][n]) ----------------
__global__ __launch_bounds__(256)
void prep_w_kernel(const float* __restrict__ W, short* __restrict__ Wt) {
    int i = blockIdx.x * 256 + threadIdx.x;
    if (i < IN_F * OUT_F) {
        int k = i / OUT_F, n = i % OUT_F;
        Wt[n * IN_F + k] = f2bf(W[i]);
    }
}

// ---------------- fc: h(bf16) = x @ W + b via MFMA ----------------
// 256 thr / 4 waves; 32 rows per wave (two 16-row MFMA subtiles), N=64 in
// four 16-col tiles, K=256 in eight 32-steps. Wt staged in LDS with XOR
// swizzle (slot ^= col&7) so B-frag ds_read_b128 is 2-way (free). A-frags
// loaded straight from global x (per-lane addr), cvt fp32->bf16 in regs.
__global__ __launch_bounds__(256, 4)
void fc_mfma_kernel(const float* __restrict__ x, const short* __restrict__ Wt,
                    const float* __restrict__ b, short* __restrict__ h, int nRows) {
    __shared__ short Wl[OUT_F * IN_F];  // 32 KB, swizzled
    {
        const uint4* src = (const uint4*)Wt;  // 2048 16B slots
        #pragma unroll
        for (int it = 0; it < 8; ++it) {
            int g = it * 256 + threadIdx.x;
            int n = g >> 5, s = g & 31;
            *(uint4*)((char*)Wl + n * 512 + (s ^ (n & 7)) * 16) = src[g];
        }
    }
    __syncthreads();

    const int wv = threadIdx.x >> 6;
    const int l  = threadIdx.x & 63;
    const int lr = l & 15;   // A row-in-tile / B col-in-tile / C col
    const int kg = l >> 4;   // k-group 0..3

    const int rowbase = (blockIdx.x * 4 + wv) * 32;
    if (rowbase >= nRows) return;

    const int ar0 = min(rowbase + lr,      nRows - 1);
    const int ar1 = min(rowbase + 16 + lr, nRows - 1);
    const float* xp0 = x + (size_t)ar0 * IN_F + kg * 8;
    const float* xp1 = x + (size_t)ar1 * IN_F + kg * 8;

    f32x4 acc[2][4];
    #pragma unroll
    for (int m = 0; m < 2; ++m)
        #pragma unroll
        for (int n = 0; n < 4; ++n) acc[m][n] = (f32x4)0.f;

    #pragma unroll
    for (int kt = 0; kt < 8; ++kt) {
        const int K0 = kt * 32;
        float4 a0lo = *(const float4*)(xp0 + K0);
        float4 a0hi = *(const float4*)(xp0 + K0 + 4);
        float4 a1lo = *(const float4*)(xp1 + K0);
        float4 a1hi = *(const float4*)(xp1 + K0 + 4);

        short8 a0, a1;
        a0[0] = f2bf(a0lo.x); a0[1] = f2bf(a0lo.y);
        a0[2] = f2bf(a0lo.z); a0[3] = f2bf(a0lo.w);
        a0[4] = f2bf(a0hi.x); a0[5] = f2bf(a0hi.y);
        a0[6] = f2bf(a0hi.z); a0[7] = f2bf(a0hi.w);
        a1[0] = f2bf(a1lo.x); a1[1] = f2bf(a1lo.y);
        a1[2] = f2bf(a1lo.z); a1[3] = f2bf(a1lo.w);
        a1[4] = f2bf(a1hi.x); a1[5] = f2bf(a1hi.y);
        a1[6] = f2bf(a1hi.z); a1[7] = f2bf(a1hi.w);

        short8 bf[4];
        #pragma unroll
        for (int nt = 0; nt < 4; ++nt) {
            const int col = nt * 16 + lr;
            const int slot = (kt * 4 + kg) ^ (col & 7);
            bf[nt] = *(const short8*)((const char*)Wl + col * 512 + slot * 16);
        }
        #pragma unroll
        for (int nt = 0; nt < 4; ++nt) {
            acc[0][nt] = __builtin_amdgcn_mfma_f32_16x16x32_bf16(a0, bf[nt], acc[0][nt], 0, 0, 0);
            acc[1][nt] = __builtin_amdgcn_mfma_f32_16x16x32_bf16(a1, bf[nt], acc[1][nt], 0, 0, 0);
        }
    }

    // epilogue: C col=lane&15, row=(lane>>4)*4+reg (m89/m91 layout)
    #pragma unroll
    for (int m = 0; m < 2; ++m) {
        #pragma unroll
        for (int nt = 0; nt < 4; ++nt) {
            const int col = nt * 16 + lr;
            const float bias = b[col];
            #pragma unroll
            for (int j = 0; j < 4; ++j) {
                const int r = rowbase + m * 16 + kg * 4 + j;
                if (r < nRows)
                    h[(size_t)r * OUT_F + col] = f2bf(acc[m][nt][j] + bias);
            }
        }
    }
}

// ---------------- CSR build ----------------
__global__ __launch_bounds__(256)
void hist_kernel(const int* __restrict__ dst, int* __restrict__ cnt, int nE) {
    for (int i = blockIdx.x * blockDim.x + threadIdx.x; i < nE;
         i += gridDim.x * blockDim.x)
        atomicAdd(&cnt[dst[i]], 1);
}

__global__ __launch_bounds__(256)
void scan1_kernel(const int* __restrict__ cnt, int* __restrict__ off,
                  int* __restrict__ part, int n) {
    __shared__ int sh[256];
    int base = blockIdx.x * 1024;
    int t = threadIdx.x;
    int v[4]; int s = 0;
    #pragma unroll
    for (int i = 0; i < 4; ++i) {
        int idx = base + t * 4 + i;
        v[i] = (idx < n) ? cnt[idx] : 0;
        s += v[i];
    }
    sh[t] = s;
    __syncthreads();
    for (int d = 1; d < 256; d <<= 1) {
        int val = (t >= d) ? sh[t - d] : 0;
        __syncthreads();
        sh[t] += val;
        __syncthreads();
    }
    if (t == 255) part[blockIdx.x] = sh[255];
    int run = (t == 0) ? 0 : sh[t - 1];
    #pragma unroll
    for (int i = 0; i < 4; ++i) {
        int idx = base + t * 4 + i;
        if (idx < n) off[idx] = run;
        run += v[i];
    }
}

__global__ __launch_bounds__(128)
void scan2_kernel(int* __restrict__ part, int nPart) {
    __shared__ int sh[128];
    int t = threadIdx.x;
    sh[t] = (t < nPart) ? part[t] : 0;
    __syncthreads();
    for (int d = 1; d < 128; d <<= 1) {
        int val = (t >= d) ? sh[t - d] : 0;
        __syncthreads();
        sh[t] += val;
        __syncthreads();
    }
    if (t < nPart) part[t] = (t == 0) ? 0 : sh[t - 1];
}

__global__ __launch_bounds__(256)
void scan3_kernel(int* __restrict__ off, const int* __restrict__ part, int n) {
    for (int i = blockIdx.x * blockDim.x + threadIdx.x; i < n;
         i += gridDim.x * blockDim.x)
        off[i] += part[i >> 10];
}

__global__ __launch_bounds__(256)
void fill_kernel(const int* __restrict__ src, const int* __restrict__ dst,
                 const float* __restrict__ w, const int* __restrict__ off,
                 int* __restrict__ cur, int2* __restrict__ pack, int nE) {
    for (int i = blockIdx.x * blockDim.x + threadIdx.x; i < nE;
         i += gridDim.x * blockDim.x) {
        int d = dst[i];
        int p = off[d] + atomicAdd(&cur[d], 1);
        pack[p] = make_int2(src[i], __float_as_int(w[i]));
    }
}

// ---------------- gather: out[n] = sum_e w_e * h[src_e] ----------------
__global__ __launch_bounds__(256)
void gather_kernel(const short* __restrict__ h, const int* __restrict__ off,
                   const int2* __restrict__ pack, float* __restrict__ out,
                   int nNodes) {
    int wid = (blockIdx.x * 256 + threadIdx.x) >> 6;
    int lane = threadIdx.x & 63;
    if (wid >= nNodes) return;
    int e = off[wid], end = off[wid + 1];
    float acc = 0.f;
    for (; e + 4 <= end; e += 4) {
        int2 p0 = pack[e + 0];
        int2 p1 = pack[e + 1];
        int2 p2 = pack[e + 2];
        int2 p3 = pack[e + 3];
        short h0 = h[(size_t)p0.x * OUT_F + lane];
        short h1 = h[(size_t)p1.x * OUT_F + lane];
        short h2 = h[(size_t)p2.x * OUT_F + lane];
        short h3 = h[(size_t)p3.x * OUT_F + lane];
        acc = fmaf(__int_as_float(p0.y), bf2f(h0), acc);
        acc = fmaf(__int_as_float(p1.y), bf2f(h1), acc);
        acc = fmaf(__int_as_float(p2.y), bf2f(h2), acc);
        acc = fmaf(__int_as_float(p3.y), bf2f(h3), acc);
    }
    for (; e < end; ++e) {
        int2 p = pack[e];
        acc = fmaf(__int_as_float(p.y), bf2f(h[(size_t)p.x * OUT_F + lane]), acc);
    }
    out[(size_t)wid * OUT_F + lane] = acc;
}

// ---------------- fallback (atomic) scatter ----------------
__global__ __launch_bounds__(256)
void scatter_kernel(const short* __restrict__ h, const int* __restrict__ src,
                    const int* __restrict__ dst, const float* __restrict__ w,
                    float* __restrict__ out, int nE) {
    int t = blockIdx.x * 256 + threadIdx.x;
    int c = t & 15;
    int stride = (gridDim.x * 256) >> 4;
    for (int e = t >> 4; e < nE; e += stride) {
        int s = src[e];
        int d = dst[e];
        float ww = w[e];
        float* op = out + (size_t)d * OUT_F + c * 4;
        const short* hp = h + (size_t)s * OUT_F + c * 4;
        unsafeAtomicAdd(op + 0, ww * bf2f(hp[0]));
        unsafeAtomicAdd(op + 1, ww * bf2f(hp[1]));
        unsafeAtomicAdd(op + 2, ww * bf2f(hp[2]));
        unsafeAtomicAdd(op + 3, ww * bf2f(hp[3]));
    }
}

static inline size_t align256(size_t x) { return (x + 255) & ~(size_t)255; }

extern "C" void kernel_launch(void* const* d_in, const int* in_sizes, int n_in,
                              void* d_out, int out_size, void* d_ws, size_t ws_size,
                              hipStream_t stream) {
    const float* x    = (const float*)d_in[0];
    const int*   esrc = (const int*)d_in[1];
    const int*   edst = (const int*)d_in[2];
    const float* ew   = (const float*)d_in[3];
    const float* W    = (const float*)d_in[4];
    const float* b    = (const float*)d_in[5];

    int nRows = in_sizes[0] / IN_F;   // 100000
    int nE    = in_sizes[1];          // 1600000
    int nOff  = nRows + 1;

    // workspace layout
    char* p = (char*)d_ws;
    size_t hB    = align256((size_t)nRows * OUT_F * sizeof(short));  // bf16 h
    size_t wtB   = align256((size_t)IN_F * OUT_F * sizeof(short));
    size_t cntB  = align256((size_t)2 * nOff * sizeof(int));
    size_t offB  = align256((size_t)nOff * sizeof(int));
    size_t partB = align256(128 * sizeof(int));
    size_t packB = align256((size_t)nE * sizeof(int2));
    size_t need  = hB + wtB + cntB + offB + partB + packB;

    short* h  = (short*)p;                p += hB;
    short* Wt = (short*)p;                p += wtB;
    int*  cnt = (int*)p;
    int*  cur = (int*)(p + (size_t)nOff * sizeof(int));
    p += cntB;
    int*  off = (int*)p;                  p += offB;
    int*  part = (int*)p;                 p += partB;
    int2* pack = (int2*)p;

    float* out = (float*)d_out;

    prep_w_kernel<<<(IN_F * OUT_F + 255) / 256, 256, 0, stream>>>(W, Wt);
    int fcBlocks = (nRows + 127) / 128;  // 4 waves * 32 rows
    fc_mfma_kernel<<<fcBlocks, 256, 0, stream>>>(x, Wt, b, h, nRows);

    if (ws_size >= need) {
        hipMemsetAsync(cnt, 0, (size_t)2 * nOff * sizeof(int), stream);
        hist_kernel<<<2048, 256, 0, stream>>>(edst, cnt, nE);
        int nPart = (nOff + 1023) / 1024;
        scan1_kernel<<<nPart, 256, 0, stream>>>(cnt, off, part, nOff);
        scan2_kernel<<<1, 128, 0, stream>>>(part, nPart);
        scan3_kernel<<<512, 256, 0, stream>>>(off, part, nOff);
        fill_kernel<<<2048, 256, 0, stream>>>(esrc, edst, ew, off, cur, pack, nE);
        int gBlocks = (nRows * 64 + 255) / 256;
        gather_kernel<<<gBlocks, 256, 0, stream>>>(h, off, pack, out, nRows);
    } else {
        hipMemsetAsync(out, 0, (size_t)out_size * sizeof(float), stream);
        scatter_kernel<<<4096, 256, 0, stream>>>(h, esrc, edst, ew, out, nE);
    }
}